// Round 5
// baseline (280.243 us; speedup 1.0000x reference)
//
#include <hip/hip_runtime.h>
#include <stdint.h>

#define DIM   768
#define NHEAD 12
#define HD    64
#define BATCH 8
#define SEQ   1024
#define MROWS (BATCH * SEQ)   // 8192
#define EPSLN 1e-5f
#define SM_M  10.0f           // fixed softmax shift; |s| <= 8 hard after LN + 1/8 scale

typedef __attribute__((ext_vector_type(8))) short s8v;   // 8 bf16 = MFMA A/B frag
typedef __attribute__((ext_vector_type(4))) short s4v;
typedef __attribute__((ext_vector_type(4))) float f32x4;

__device__ inline short f2bf(float f) {
    union { float f; unsigned u; } v; v.f = f;
    unsigned r = v.u + 0x7FFFu + ((v.u >> 16) & 1u);   // RNE
    return (short)(r >> 16);
}
// pack two fp32 -> two bf16 in one u32 via v_perm (round-half-up; inputs
// are finite activations, tie-bias is negligible vs bf16 ulp)
__device__ inline unsigned pk2bf(float lo, float hi) {
    union { float f; unsigned u; } a, b; a.f = lo; b.f = hi;
    return __builtin_amdgcn_perm(b.u + 0x8000u, a.u + 0x8000u, 0x07060302u);
}

// ---------------------------------------------------------------------------
// single fp32 -> bf16 conversion pass over x | qkv_w | proj_w (float4 units)
// ---------------------------------------------------------------------------
#define N4_X (MROWS * DIM / 4)          // 1572864
#define N4_W1 (3 * DIM * DIM / 4)       // 442368
#define N4_W2 (DIM * DIM / 4)           // 147456
__global__ __launch_bounds__(256) void cvt_all(
    const float* __restrict__ x, const float* __restrict__ w1,
    const float* __restrict__ w2, short* __restrict__ dx,
    short* __restrict__ dw1, short* __restrict__ dw2)
{
    size_t i = (size_t)blockIdx.x * 256 + threadIdx.x;
    const float* s; short* d;
    if (i < N4_X)                { s = x  + i * 4;               d = dx  + i * 4; }
    else if (i < N4_X + N4_W1)   { size_t j = i - N4_X;          s = w1 + j * 4; d = dw1 + j * 4; }
    else                         { size_t j = i - N4_X - N4_W1;  s = w2 + j * 4; d = dw2 + j * 4; }
    float4 v = *(const float4*)s;
    uint2 o; o.x = pk2bf(v.x, v.y); o.y = pk2bf(v.z, v.w);
    *(uint2*)d = o;
}

// ---------------------------------------------------------------------------
// bf16 MFMA GEMM, register-pipelined, double-buffered LDS, ONE barrier/iter.
// C = A @ W^T + bias. A[M][768], W[N][768]. 128x128 tile, 256 thr = 4 waves
// (2x2 of 64x64), BK=32, 16x16x32 MFMA.
// Pipeline: ds_write(regs,buf) -> barrier -> ds_read frags(buf) ->
//           global prefetch next slab into regs -> MFMA  (vmcnt wait for the
//           prefetch lands at the NEXT ds_write, hidden behind MFMA).
// qkv_mode: fused LayerNorm(64) on q,k (q also scaled by 1/8) -> bf16
//           [B,H,N,64]; v -> bf16 transposed [B,H,64,N].
// plain:    fp32 out [M][Ncols] + bias.
// ---------------------------------------------------------------------------
__global__ __launch_bounds__(256) void gemm_mfma(
    const short* __restrict__ A, const short* __restrict__ W,
    const float* __restrict__ bias,
    short* __restrict__ oq, short* __restrict__ ok, short* __restrict__ ov,
    float* __restrict__ oplain,
    const float* __restrict__ gamma, const float* __restrict__ beta,
    int Ncols, int qkv_mode)
{
    __shared__ __align__(16) short As[2][128 * 32];
    __shared__ __align__(16) short Bs[2][128 * 32];

    const int tid  = threadIdx.x;
    const int m0   = blockIdx.y * 128;
    const int n0   = blockIdx.x * 128;
    const int w    = tid >> 6, lane = tid & 63;
    const int quad = lane >> 4, l16 = lane & 15;
    const int wm   = (w & 1) * 64, wn = (w >> 1) * 64;

    s8v ar[2], br[2];
    auto loadslab = [&](int kk) {
#pragma unroll
        for (int i = 0; i < 2; ++i) {
            int f = i * 256 + tid;
            int row = f >> 2, ch = (f & 3) * 8;
            ar[i] = *(const s8v*)&A[(size_t)(m0 + row) * DIM + kk + ch];
            br[i] = *(const s8v*)&W[(size_t)(n0 + row) * DIM + kk + ch];
        }
    };

    f32x4 acc[4][4];
#pragma unroll
    for (int i = 0; i < 4; ++i)
#pragma unroll
        for (int j = 0; j < 4; ++j) acc[i][j] = (f32x4){0.f, 0.f, 0.f, 0.f};

    loadslab(0);
#pragma unroll 2
    for (int k0 = 0; k0 < DIM; k0 += 32) {
        const int buf = (k0 >> 5) & 1;
#pragma unroll
        for (int i = 0; i < 2; ++i) {
            int f = i * 256 + tid;
            *(s8v*)&As[buf][f * 8] = ar[i];
            *(s8v*)&Bs[buf][f * 8] = br[i];
        }
        __syncthreads();   // writes to buf visible; prior-iter reads of buf done
        s8v af[4], bw[4];
#pragma unroll
        for (int t = 0; t < 4; ++t) {
            af[t] = *(const s8v*)&As[buf][(wm + t * 16 + l16) * 32 + quad * 8];
            bw[t] = *(const s8v*)&Bs[buf][(wn + t * 16 + l16) * 32 + quad * 8];
        }
        loadslab(k0 + 32 < DIM ? k0 + 32 : 0);   // prefetch (wraps harmlessly)
#pragma unroll
        for (int mt = 0; mt < 4; ++mt)
#pragma unroll
            for (int nt = 0; nt < 4; ++nt)
                acc[mt][nt] = __builtin_amdgcn_mfma_f32_16x16x32_bf16(
                    af[mt], bw[nt], acc[mt][nt], 0, 0, 0);
    }

    // C layout per 16x16 tile: row m = quad*4 + i, col n = l16
    if (qkv_mode) {
        const int which = n0 / DIM;        // 0=q, 1=k, 2=v
        const int nb = n0 + wn;            // wave's 64-col span = one head
        const int hh = (nb - which * DIM) >> 6;
        if (which == 2) {
#pragma unroll
            for (int mt = 0; mt < 4; ++mt)
#pragma unroll
                for (int nt = 0; nt < 4; ++nt)
#pragma unroll
                    for (int i = 0; i < 4; ++i) {
                        int m = m0 + wm + mt * 16 + quad * 4 + i;
                        int e = nt * 16 + l16;
                        float cv = acc[mt][nt][i] + bias[nb + e];
                        int bb = m >> 10, nn = m & 1023;
                        ov[(((size_t)(bb * NHEAD + hh)) * HD + e) * SEQ + nn] = f2bf(cv);
                    }
        } else {
            short* dst = which ? ok : oq;
            const float qscale = (which == 0) ? 0.125f : 1.0f;
            float g[4], be[4], bi[4];
#pragma unroll
            for (int nt = 0; nt < 4; ++nt) {
                g[nt]  = gamma[nt * 16 + l16];
                be[nt] = beta [nt * 16 + l16];
                bi[nt] = bias [nb + nt * 16 + l16];
            }
#pragma unroll
            for (int mt = 0; mt < 4; ++mt)
#pragma unroll
                for (int i = 0; i < 4; ++i) {
                    float v0 = acc[mt][0][i] + bi[0];
                    float v1 = acc[mt][1][i] + bi[1];
                    float v2 = acc[mt][2][i] + bi[2];
                    float v3 = acc[mt][3][i] + bi[3];
                    float s  = (v0 + v1) + (v2 + v3);
                    float s2 = (v0 * v0 + v1 * v1) + (v2 * v2 + v3 * v3);
#pragma unroll
                    for (int mm = 1; mm < 16; mm <<= 1) {
                        s  += __shfl_xor(s,  mm);
                        s2 += __shfl_xor(s2, mm);
                    }
                    float mu  = s * (1.f / 64.f);
                    float var = s2 * (1.f / 64.f) - mu * mu;
                    float rsq = rsqrtf(var + EPSLN);
                    int m = m0 + wm + mt * 16 + quad * 4 + i;
                    int bb = m >> 10, nn = m & 1023;
                    size_t rb = (((size_t)(bb * NHEAD + hh)) * SEQ + nn) * HD;
                    float vv[4] = {v0, v1, v2, v3};
#pragma unroll
                    for (int nt = 0; nt < 4; ++nt) {
                        float o = ((vv[nt] - mu) * rsq * g[nt] + be[nt]) * qscale;
                        dst[rb + nt * 16 + l16] = f2bf(o);
                    }
                }
        }
    } else {
#pragma unroll
        for (int mt = 0; mt < 4; ++mt)
#pragma unroll
            for (int nt = 0; nt < 4; ++nt)
#pragma unroll
                for (int i = 0; i < 4; ++i) {
                    int m = m0 + wm + mt * 16 + quad * 4 + i;
                    int n = n0 + wn + nt * 16 + l16;
                    oplain[(size_t)m * Ncols + n] = acc[mt][nt][i] + bias[n];
                }
    }
}

// ---------------------------------------------------------------------------
// MFMA flash attention, key-split waves, S^T formulation.
// Block = 4 waves, one (b,h) x 64 q-rows; wave w owns keys jb*128+w*32..+31.
// S^T = K . Q^T: BOTH operands load global->register (K rows = A-frags,
// Q rows = B-frags, each contiguous b128). C-fragment holds 4 consecutive
// KEYS per lane -> P[q][key] written with packed b64 (8 stores/jb vs 32
// scalar in the S formulation). PV: O^T = V^T . P^T, P^T B-frags are
// contiguous b128 rows of P[q][*]. No barriers in the main loop.
// Fixed-shift softmax p = exp(s - 10); cross-wave combine is a plain sum.
// ---------------------------------------------------------------------------
__global__ __launch_bounds__(256) void attn_mfma(
    const short* __restrict__ q, const short* __restrict__ k,
    const short* __restrict__ vt, short* __restrict__ O)
{
    const int bh   = blockIdx.y;
    const int b    = bh / NHEAD;
    const int h    = bh % NHEAD;
    const int q0   = blockIdx.x * 64;
    const int tid  = threadIdx.x;
    const int w    = tid >> 6;
    const int lane = tid & 63;
    const int quad = lane >> 4;
    const int l16  = lane & 15;

    __shared__ __align__(16) char smem[20480];   // P (main loop) / Obuf (epilogue)
    __shared__ float denom[4][64];

    short (*Pw)[40]   = (short(*)[40])(smem + (size_t)w * (64 * 40 * 2));
    float (*Obuf)[68] = (float(*)[68])smem;      // [64 q][64 e + pad]

    const size_t base   = (size_t)bh * SEQ * HD;
    const size_t vtbase = (size_t)bh * HD * SEQ;

    // hoist Q B-frags: B[k=d][n=q]: lane -> q = qt*16+l16, d = hf*32+quad*8+jj
    s8v qB[4][2];
#pragma unroll
    for (int qt = 0; qt < 4; ++qt)
#pragma unroll
        for (int hf = 0; hf < 2; ++hf)
            qB[qt][hf] = *(const s8v*)&q[base + (size_t)(q0 + qt * 16 + l16) * HD
                                         + hf * 32 + quad * 8];

    f32x4 oacc[4][4];                 // [et][qt] : O^T partials
    float lacc[4] = {0.f, 0.f, 0.f, 0.f};
#pragma unroll
    for (int a = 0; a < 4; ++a)
#pragma unroll
        for (int c = 0; c < 4; ++c) oacc[a][c] = (f32x4){0.f, 0.f, 0.f, 0.f};

#pragma unroll 2
    for (int jb = 0; jb < 8; ++jb) {
        const int kb = jb * 128 + w * 32;    // this wave's 32-key window

        // K A-frags: A[m=key][k=d]: lane -> key = kt*16+l16, d = hf*32+quad*8+jj
        s8v kA[2][2];
#pragma unroll
        for (int kt = 0; kt < 2; ++kt)
#pragma unroll
            for (int hf = 0; hf < 2; ++hf)
                kA[kt][hf] = *(const s8v*)&k[base + (size_t)(kb + kt * 16 + l16) * HD
                                             + hf * 32 + quad * 8];
        // V^T A-frags: A[m=e][k=key]: lane -> e = et*16+l16, key = quad*8+jj
        s8v va[4];
#pragma unroll
        for (int et = 0; et < 4; ++et)
            va[et] = *(const s8v*)&vt[vtbase + (size_t)(et * 16 + l16) * SEQ
                                      + kb + quad * 8];

        // ---- S^T = K Q^T, exp, packed P[q][key] -> LDS ----
#pragma unroll
        for (int qt = 0; qt < 4; ++qt)
#pragma unroll
            for (int kt = 0; kt < 2; ++kt) {
                f32x4 c = (f32x4){0.f, 0.f, 0.f, 0.f};
                c = __builtin_amdgcn_mfma_f32_16x16x32_bf16(kA[kt][0], qB[qt][0], c, 0, 0, 0);
                c = __builtin_amdgcn_mfma_f32_16x16x32_bf16(kA[kt][1], qB[qt][1], c, 0, 0, 0);
                // C: (key = kt*16 + quad*4 + i, q = qt*16 + l16)
                float p0 = __expf(c[0] - SM_M), p1 = __expf(c[1] - SM_M);
                float p2 = __expf(c[2] - SM_M), p3 = __expf(c[3] - SM_M);
                lacc[qt] += (p0 + p1) + (p2 + p3);
                uint2 pk; pk.x = pk2bf(p0, p1); pk.y = pk2bf(p2, p3);
                *(uint2*)&Pw[qt * 16 + l16][kt * 16 + quad * 4] = pk;   // b64
            }

        // ---- P^T B-frags: B[k=key][n=q] = Pw[q][key], contiguous b128 ----
        s8v pb[4];
#pragma unroll
        for (int qt = 0; qt < 4; ++qt)
            pb[qt] = *(const s8v*)&Pw[qt * 16 + l16][quad * 8];

        // ---- O^T += V^T P^T (K = 32: one MFMA per tile) ----
#pragma unroll
        for (int et = 0; et < 4; ++et)
#pragma unroll
            for (int qt = 0; qt < 4; ++qt)
                oacc[et][qt] = __builtin_amdgcn_mfma_f32_16x16x32_bf16(
                    va[et], pb[qt], oacc[et][qt], 0, 0, 0);
    }

    // ---- denominator: lane holds col q = qt*16+l16; sum across quads ----
#pragma unroll
    for (int qt = 0; qt < 4; ++qt) {
        float s = lacc[qt];
        s += __shfl_xor(s, 16);
        s += __shfl_xor(s, 32);
        denom[w][qt * 16 + l16] = s;     // 4 quads write same value: benign
    }
    __syncthreads();                     // main loop done; P region now dead

    // ---- cross-wave O sum into Obuf (overlaid on P) ----
    for (int r = 0; r < 4; ++r) {
        if (w == r) {
#pragma unroll
            for (int et = 0; et < 4; ++et)
#pragma unroll
                for (int qt = 0; qt < 4; ++qt)
#pragma unroll
                    for (int i = 0; i < 4; ++i) {
                        int e  = et * 16 + quad * 4 + i;
                        int qq = qt * 16 + l16;
                        if (r == 0) Obuf[qq][e]  = oacc[et][qt][i];
                        else        Obuf[qq][e] += oacc[et][qt][i];
                    }
        }
        __syncthreads();
    }

    // ---- scale + store: thread t -> (q = t/4, e-span = (t%4)*16) ----
    const int qq = tid >> 2;
    const int e0 = (tid & 3) * 16;
    float linv = 1.0f / (denom[0][qq] + denom[1][qq] + denom[2][qq] + denom[3][qq]);
    short* op = &O[((size_t)b * SEQ + q0 + qq) * DIM + h * HD + e0];
    uint4 o1, o2;
    o1.x = pk2bf(Obuf[qq][e0 +  0] * linv, Obuf[qq][e0 +  1] * linv);
    o1.y = pk2bf(Obuf[qq][e0 +  2] * linv, Obuf[qq][e0 +  3] * linv);
    o1.z = pk2bf(Obuf[qq][e0 +  4] * linv, Obuf[qq][e0 +  5] * linv);
    o1.w = pk2bf(Obuf[qq][e0 +  6] * linv, Obuf[qq][e0 +  7] * linv);
    o2.x = pk2bf(Obuf[qq][e0 +  8] * linv, Obuf[qq][e0 +  9] * linv);
    o2.y = pk2bf(Obuf[qq][e0 + 10] * linv, Obuf[qq][e0 + 11] * linv);
    o2.z = pk2bf(Obuf[qq][e0 + 12] * linv, Obuf[qq][e0 + 13] * linv);
    o2.w = pk2bf(Obuf[qq][e0 + 14] * linv, Obuf[qq][e0 + 15] * linv);
    *(uint4*)&op[0] = o1;
    *(uint4*)&op[8] = o2;
}

// ---------------------------------------------------------------------------
extern "C" void kernel_launch(void* const* d_in, const int* in_sizes, int n_in,
                              void* d_out, int out_size, void* d_ws, size_t ws_size,
                              hipStream_t stream)
{
    const float* x      = (const float*)d_in[0];
    const float* qkv_w  = (const float*)d_in[1];
    const float* qkv_b  = (const float*)d_in[2];
    const float* proj_w = (const float*)d_in[3];
    const float* proj_b = (const float*)d_in[4];
    const float* gamma  = (const float*)d_in[5];
    const float* beta   = (const float*)d_in[6];
    float* out = (float*)d_out;

    const size_t PER = (size_t)BATCH * NHEAD * SEQ * HD;  // 6291456
    short* qb  = (short*)d_ws;                 // bf16 q   [B,H,N,64] (LN'd, x1/8)
    short* kb  = qb + PER;                     // bf16 k   [B,H,N,64] (LN'd)
    short* vtb = kb + PER;                     // bf16 v^T [B,H,64,N]
    short* ob  = vtb + PER;                    // bf16 o   [B,N,768]
    short* xb  = ob + PER;                     // bf16 x   [8192,768]
    short* wqb = xb + (size_t)MROWS * DIM;     // bf16 qkv_w [2304,768]
    short* wpb = wqb + (size_t)3 * DIM * DIM;  // bf16 proj_w [768,768]

    // 0) one fused fp32 -> bf16 conversion pass
    cvt_all<<<dim3((N4_X + N4_W1 + N4_W2) / 256), 256, 0, stream>>>(
        x, qkv_w, proj_w, xb, wqb, wpb);

    // 1) qkv GEMM + fused LN -> q,k bf16 [B,H,N,64]; v bf16 transposed
    gemm_mfma<<<dim3(2304 / 128, MROWS / 128), 256, 0, stream>>>(
        xb, wqb, qkv_b, qb, kb, vtb, nullptr, gamma, beta, 2304, 1);

    // 2) MFMA flash attention (key-split, S^T) -> o bf16 [B,N,768]
    attn_mfma<<<dim3(SEQ / 64, BATCH * NHEAD), 256, 0, stream>>>(qb, kb, vtb, ob);

    // 3) out = o @ proj_w^T + proj_b (fp32 out)
    gemm_mfma<<<dim3(DIM / 128, MROWS / 128), 256, 0, stream>>>(
        ob, wpb, proj_b, nullptr, nullptr, nullptr, out, nullptr, nullptr, DIM, 0);
}

// Round 6
// 273.446 us; speedup vs baseline: 1.0249x; 1.0249x over previous
//
#include <hip/hip_runtime.h>
#include <stdint.h>

#define DIM   768
#define NHEAD 12
#define HD    64
#define BATCH 8
#define SEQ   1024
#define MROWS (BATCH * SEQ)   // 8192
#define EPSLN 1e-5f
#define SM_M  10.0f           // fixed softmax shift; |s| <= 8 hard after LN + 1/8 scale

typedef __attribute__((ext_vector_type(8))) short s8v;   // 8 bf16 = MFMA A/B frag
typedef __attribute__((ext_vector_type(4))) short s4v;
typedef __attribute__((ext_vector_type(4))) float f32x4;

__device__ inline short f2bf(float f) {
    union { float f; unsigned u; } v; v.f = f;
    unsigned r = v.u + 0x7FFFu + ((v.u >> 16) & 1u);   // RNE
    return (short)(r >> 16);
}
// pack two fp32 -> two bf16 in one u32 via v_perm (round-half-up)
__device__ inline unsigned pk2bf(float lo, float hi) {
    union { float f; unsigned u; } a, b; a.f = lo; b.f = hi;
    return __builtin_amdgcn_perm(b.u + 0x8000u, a.u + 0x8000u, 0x07060302u);
}
// async global->LDS, 16 B per lane (LDS dst is wave-uniform base + lane*16)
__device__ inline void gload16(const void* g, void* l) {
    __builtin_amdgcn_global_load_lds(
        (const __attribute__((address_space(1))) void*)g,
        (__attribute__((address_space(3))) void*)l, 16, 0, 0);
}

// ---------------------------------------------------------------------------
// single fp32 -> bf16 conversion pass over x | qkv_w | proj_w (float4 units)
// ---------------------------------------------------------------------------
#define N4_X (MROWS * DIM / 4)          // 1572864
#define N4_W1 (3 * DIM * DIM / 4)       // 442368
#define N4_W2 (DIM * DIM / 4)           // 147456
__global__ __launch_bounds__(256) void cvt_all(
    const float* __restrict__ x, const float* __restrict__ w1,
    const float* __restrict__ w2, short* __restrict__ dx,
    short* __restrict__ dw1, short* __restrict__ dw2)
{
    size_t i = (size_t)blockIdx.x * 256 + threadIdx.x;
    const float* s; short* d;
    if (i < N4_X)                { s = x  + i * 4;               d = dx  + i * 4; }
    else if (i < N4_X + N4_W1)   { size_t j = i - N4_X;          s = w1 + j * 4; d = dw1 + j * 4; }
    else                         { size_t j = i - N4_X - N4_W1;  s = w2 + j * 4; d = dw2 + j * 4; }
    float4 v = *(const float4*)s;
    uint2 o; o.x = pk2bf(v.x, v.y); o.y = pk2bf(v.z, v.w);
    *(uint2*)d = o;
}

// ---------------------------------------------------------------------------
// bf16 MFMA GEMM: C = A @ W^T + bias. A[M][768], W[N][768]. 128x128 tile,
// 256 thr = 4 waves (2x2 of 64x64), BK=32, 16x16x32 MFMA.
// K-loop: double-buffered LDS fed by global_load_lds (NO staging registers),
// ONE barrier per iter; prefetch of slab k+1 issues right after the barrier
// and completes during ds_read+MFMA of slab k, so the barrier drain is ~free.
// Bank-conflict fix: source-chunk XOR swizzle c = c' ^ ((row>>1)&3) at stage
// time (gload16 forbids padding; swizzling the SOURCE is free) -> the b128
// frag reads hit all 8 (parity x chunk) spans, 2 lanes each = conflict-free.
// qkv_mode: fused LayerNorm(64) on q,k (q also scaled by 1/8) -> bf16
//           [B,H,N,64]; v -> bf16 transposed [B,H,64,N].
// plain:    fp32 out [M][Ncols] + bias.
// ---------------------------------------------------------------------------
__global__ __launch_bounds__(256) void gemm_mfma(
    const short* __restrict__ A, const short* __restrict__ W,
    const float* __restrict__ bias,
    short* __restrict__ oq, short* __restrict__ ok, short* __restrict__ ov,
    float* __restrict__ oplain,
    const float* __restrict__ gamma, const float* __restrict__ beta,
    int Ncols, int qkv_mode)
{
    __shared__ __align__(16) short As[2][128 * 32];
    __shared__ __align__(16) short Bs[2][128 * 32];

    const int tid  = threadIdx.x;
    const int m0   = blockIdx.y * 128;
    const int n0   = blockIdx.x * 128;
    const int w    = tid >> 6, lane = tid & 63;
    const int quad = lane >> 4, l16 = lane & 15;
    const int wm   = (w & 1) * 64, wn = (w >> 1) * 64;
    const int swz  = (l16 >> 1) & 3;          // frag-read chunk swizzle
    const int cswz = (quad ^ swz) * 8;        // k-offset within a row's 32

    auto stage = [&](int kk, int buf) {
#pragma unroll
        for (int i = 0; i < 2; ++i) {
            int f   = i * 256 + tid;          // 0..511 -> LDS cell f*16B
            int row = f >> 2;
            int c   = (f & 3) ^ ((row >> 1) & 3);   // source chunk for this cell
            gload16(&A[(size_t)(m0 + row) * DIM + kk + c * 8], &As[buf][f * 8]);
            gload16(&W[(size_t)(n0 + row) * DIM + kk + c * 8], &Bs[buf][f * 8]);
        }
    };

    f32x4 acc[4][4];
#pragma unroll
    for (int i = 0; i < 4; ++i)
#pragma unroll
        for (int j = 0; j < 4; ++j) acc[i][j] = (f32x4){0.f, 0.f, 0.f, 0.f};

    stage(0, 0);
#pragma unroll 2
    for (int k0 = 0; k0 < DIM; k0 += 32) {
        const int buf = (k0 >> 5) & 1;
        __syncthreads();                 // drains this buf's loads; buf^1 free
        if (k0 + 32 < DIM) stage(k0 + 32, buf ^ 1);   // prefetch (async)
        s8v af[4], bw[4];
#pragma unroll
        for (int t = 0; t < 4; ++t) {
            af[t] = *(const s8v*)&As[buf][(wm + t * 16 + l16) * 32 + cswz];
            bw[t] = *(const s8v*)&Bs[buf][(wn + t * 16 + l16) * 32 + cswz];
        }
#pragma unroll
        for (int mt = 0; mt < 4; ++mt)
#pragma unroll
            for (int nt = 0; nt < 4; ++nt)
                acc[mt][nt] = __builtin_amdgcn_mfma_f32_16x16x32_bf16(
                    af[mt], bw[nt], acc[mt][nt], 0, 0, 0);
    }

    // C layout per 16x16 tile: row m = quad*4 + i, col n = l16
    if (qkv_mode) {
        const int which = n0 / DIM;        // 0=q, 1=k, 2=v
        const int nb = n0 + wn;            // wave's 64-col span = one head
        const int hh = (nb - which * DIM) >> 6;
        if (which == 2) {
#pragma unroll
            for (int mt = 0; mt < 4; ++mt)
#pragma unroll
                for (int nt = 0; nt < 4; ++nt)
#pragma unroll
                    for (int i = 0; i < 4; ++i) {
                        int m = m0 + wm + mt * 16 + quad * 4 + i;
                        int e = nt * 16 + l16;
                        float cv = acc[mt][nt][i] + bias[nb + e];
                        int bb = m >> 10, nn = m & 1023;
                        ov[(((size_t)(bb * NHEAD + hh)) * HD + e) * SEQ + nn] = f2bf(cv);
                    }
        } else {
            short* dst = which ? ok : oq;
            const float qscale = (which == 0) ? 0.125f : 1.0f;
            float g[4], be[4], bi[4];
#pragma unroll
            for (int nt = 0; nt < 4; ++nt) {
                g[nt]  = gamma[nt * 16 + l16];
                be[nt] = beta [nt * 16 + l16];
                bi[nt] = bias [nb + nt * 16 + l16];
            }
#pragma unroll
            for (int mt = 0; mt < 4; ++mt)
#pragma unroll
                for (int i = 0; i < 4; ++i) {
                    float v0 = acc[mt][0][i] + bi[0];
                    float v1 = acc[mt][1][i] + bi[1];
                    float v2 = acc[mt][2][i] + bi[2];
                    float v3 = acc[mt][3][i] + bi[3];
                    float s  = (v0 + v1) + (v2 + v3);
                    float s2 = (v0 * v0 + v1 * v1) + (v2 * v2 + v3 * v3);
#pragma unroll
                    for (int mm = 1; mm < 16; mm <<= 1) {
                        s  += __shfl_xor(s,  mm);
                        s2 += __shfl_xor(s2, mm);
                    }
                    float mu  = s * (1.f / 64.f);
                    float var = s2 * (1.f / 64.f) - mu * mu;
                    float rsq = rsqrtf(var + EPSLN);
                    int m = m0 + wm + mt * 16 + quad * 4 + i;
                    int bb = m >> 10, nn = m & 1023;
                    size_t rb = (((size_t)(bb * NHEAD + hh)) * SEQ + nn) * HD;
                    float vv[4] = {v0, v1, v2, v3};
#pragma unroll
                    for (int nt = 0; nt < 4; ++nt) {
                        float o = ((vv[nt] - mu) * rsq * g[nt] + be[nt]) * qscale;
                        dst[rb + nt * 16 + l16] = f2bf(o);
                    }
                }
        }
    } else {
#pragma unroll
        for (int mt = 0; mt < 4; ++mt)
#pragma unroll
            for (int nt = 0; nt < 4; ++nt)
#pragma unroll
                for (int i = 0; i < 4; ++i) {
                    int m = m0 + wm + mt * 16 + quad * 4 + i;
                    int n = n0 + wn + nt * 16 + l16;
                    oplain[(size_t)m * Ncols + n] = acc[mt][nt][i] + bias[n];
                }
    }
}

// ---------------------------------------------------------------------------
// MFMA flash attention, key-split waves, S^T formulation.
// Block = 4 waves, one (b,h) x 64 q-rows; wave w owns keys jb*128+w*32..+31.
// S^T = K . Q^T: BOTH operands load global->register (contiguous b128).
// C-fragment holds 4 consecutive KEYS per lane -> packed b64 P writes.
// PV: O^T = V^T . P^T, P^T B-frags are contiguous b128 rows of P[q][*].
// No barriers in the main loop. Fixed-shift softmax p = exp(s - 10);
// cross-wave combine is a plain sum (disjoint keys).
// ---------------------------------------------------------------------------
__global__ __launch_bounds__(256) void attn_mfma(
    const short* __restrict__ q, const short* __restrict__ k,
    const short* __restrict__ vt, short* __restrict__ O)
{
    const int bh   = blockIdx.y;
    const int b    = bh / NHEAD;
    const int h    = bh % NHEAD;
    const int q0   = blockIdx.x * 64;
    const int tid  = threadIdx.x;
    const int w    = tid >> 6;
    const int lane = tid & 63;
    const int quad = lane >> 4;
    const int l16  = lane & 15;

    __shared__ __align__(16) char smem[20480];   // P (main loop) / Obuf (epilogue)
    __shared__ float denom[4][64];

    short (*Pw)[40]   = (short(*)[40])(smem + (size_t)w * (64 * 40 * 2));
    float (*Obuf)[68] = (float(*)[68])smem;      // [64 q][64 e + pad]

    const size_t base   = (size_t)bh * SEQ * HD;
    const size_t vtbase = (size_t)bh * HD * SEQ;

    // hoist Q B-frags: B[k=d][n=q]: lane -> q = qt*16+l16, d = hf*32+quad*8+jj
    s8v qB[4][2];
#pragma unroll
    for (int qt = 0; qt < 4; ++qt)
#pragma unroll
        for (int hf = 0; hf < 2; ++hf)
            qB[qt][hf] = *(const s8v*)&q[base + (size_t)(q0 + qt * 16 + l16) * HD
                                         + hf * 32 + quad * 8];

    f32x4 oacc[4][4];                 // [et][qt] : O^T partials
    float lacc[4] = {0.f, 0.f, 0.f, 0.f};
#pragma unroll
    for (int a = 0; a < 4; ++a)
#pragma unroll
        for (int c = 0; c < 4; ++c) oacc[a][c] = (f32x4){0.f, 0.f, 0.f, 0.f};

#pragma unroll 2
    for (int jb = 0; jb < 8; ++jb) {
        const int kb = jb * 128 + w * 32;    // this wave's 32-key window

        // K A-frags: A[m=key][k=d]: lane -> key = kt*16+l16, d = hf*32+quad*8+jj
        s8v kA[2][2];
#pragma unroll
        for (int kt = 0; kt < 2; ++kt)
#pragma unroll
            for (int hf = 0; hf < 2; ++hf)
                kA[kt][hf] = *(const s8v*)&k[base + (size_t)(kb + kt * 16 + l16) * HD
                                             + hf * 32 + quad * 8];
        // V^T A-frags: A[m=e][k=key]: lane -> e = et*16+l16, key = quad*8+jj
        s8v va[4];
#pragma unroll
        for (int et = 0; et < 4; ++et)
            va[et] = *(const s8v*)&vt[vtbase + (size_t)(et * 16 + l16) * SEQ
                                      + kb + quad * 8];

        // ---- S^T = K Q^T, exp, packed P[q][key] -> LDS ----
#pragma unroll
        for (int qt = 0; qt < 4; ++qt)
#pragma unroll
            for (int kt = 0; kt < 2; ++kt) {
                f32x4 c = (f32x4){0.f, 0.f, 0.f, 0.f};
                c = __builtin_amdgcn_mfma_f32_16x16x32_bf16(kA[kt][0], qB[qt][0], c, 0, 0, 0);
                c = __builtin_amdgcn_mfma_f32_16x16x32_bf16(kA[kt][1], qB[qt][1], c, 0, 0, 0);
                // C: (key = kt*16 + quad*4 + i, q = qt*16 + l16)
                float p0 = __expf(c[0] - SM_M), p1 = __expf(c[1] - SM_M);
                float p2 = __expf(c[2] - SM_M), p3 = __expf(c[3] - SM_M);
                lacc[qt] += (p0 + p1) + (p2 + p3);
                uint2 pk; pk.x = pk2bf(p0, p1); pk.y = pk2bf(p2, p3);
                *(uint2*)&Pw[qt * 16 + l16][kt * 16 + quad * 4] = pk;   // b64
            }

        // ---- P^T B-frags: B[k=key][n=q] = Pw[q][key], contiguous b128 ----
        s8v pb[4];
#pragma unroll
        for (int qt = 0; qt < 4; ++qt)
            pb[qt] = *(const s8v*)&Pw[qt * 16 + l16][quad * 8];

        // ---- O^T += V^T P^T (K = 32: one MFMA per tile) ----
#pragma unroll
        for (int et = 0; et < 4; ++et)
#pragma unroll
            for (int qt = 0; qt < 4; ++qt)
                oacc[et][qt] = __builtin_amdgcn_mfma_f32_16x16x32_bf16(
                    va[et], pb[qt], oacc[et][qt], 0, 0, 0);
    }

    // ---- denominator: lane holds col q = qt*16+l16; sum across quads ----
#pragma unroll
    for (int qt = 0; qt < 4; ++qt) {
        float s = lacc[qt];
        s += __shfl_xor(s, 16);
        s += __shfl_xor(s, 32);
        denom[w][qt * 16 + l16] = s;     // 4 quads write same value: benign
    }
    __syncthreads();                     // main loop done; P region now dead

    // ---- cross-wave O sum into Obuf (overlaid on P) ----
    for (int r = 0; r < 4; ++r) {
        if (w == r) {
#pragma unroll
            for (int et = 0; et < 4; ++et)
#pragma unroll
                for (int qt = 0; qt < 4; ++qt)
#pragma unroll
                    for (int i = 0; i < 4; ++i) {
                        int e  = et * 16 + quad * 4 + i;
                        int qq = qt * 16 + l16;
                        if (r == 0) Obuf[qq][e]  = oacc[et][qt][i];
                        else        Obuf[qq][e] += oacc[et][qt][i];
                    }
        }
        __syncthreads();
    }

    // ---- scale + store: thread t -> (q = t/4, e-span = (t%4)*16) ----
    const int qq = tid >> 2;
    const int e0 = (tid & 3) * 16;
    float linv = 1.0f / (denom[0][qq] + denom[1][qq] + denom[2][qq] + denom[3][qq]);
    short* op = &O[((size_t)b * SEQ + q0 + qq) * DIM + h * HD + e0];
    uint4 o1, o2;
    o1.x = pk2bf(Obuf[qq][e0 +  0] * linv, Obuf[qq][e0 +  1] * linv);
    o1.y = pk2bf(Obuf[qq][e0 +  2] * linv, Obuf[qq][e0 +  3] * linv);
    o1.z = pk2bf(Obuf[qq][e0 +  4] * linv, Obuf[qq][e0 +  5] * linv);
    o1.w = pk2bf(Obuf[qq][e0 +  6] * linv, Obuf[qq][e0 +  7] * linv);
    o2.x = pk2bf(Obuf[qq][e0 +  8] * linv, Obuf[qq][e0 +  9] * linv);
    o2.y = pk2bf(Obuf[qq][e0 + 10] * linv, Obuf[qq][e0 + 11] * linv);
    o2.z = pk2bf(Obuf[qq][e0 + 12] * linv, Obuf[qq][e0 + 13] * linv);
    o2.w = pk2bf(Obuf[qq][e0 + 14] * linv, Obuf[qq][e0 + 15] * linv);
    *(uint4*)&op[0] = o1;
    *(uint4*)&op[8] = o2;
}

// ---------------------------------------------------------------------------
extern "C" void kernel_launch(void* const* d_in, const int* in_sizes, int n_in,
                              void* d_out, int out_size, void* d_ws, size_t ws_size,
                              hipStream_t stream)
{
    const float* x      = (const float*)d_in[0];
    const float* qkv_w  = (const float*)d_in[1];
    const float* qkv_b  = (const float*)d_in[2];
    const float* proj_w = (const float*)d_in[3];
    const float* proj_b = (const float*)d_in[4];
    const float* gamma  = (const float*)d_in[5];
    const float* beta   = (const float*)d_in[6];
    float* out = (float*)d_out;

    const size_t PER = (size_t)BATCH * NHEAD * SEQ * HD;  // 6291456
    short* qb  = (short*)d_ws;                 // bf16 q   [B,H,N,64] (LN'd, x1/8)
    short* kb  = qb + PER;                     // bf16 k   [B,H,N,64] (LN'd)
    short* vtb = kb + PER;                     // bf16 v^T [B,H,64,N]
    short* ob  = vtb + PER;                    // bf16 o   [B,N,768]
    short* xb  = ob + PER;                     // bf16 x   [8192,768]
    short* wqb = xb + (size_t)MROWS * DIM;     // bf16 qkv_w [2304,768]
    short* wpb = wqb + (size_t)3 * DIM * DIM;  // bf16 proj_w [768,768]

    // 0) one fused fp32 -> bf16 conversion pass
    cvt_all<<<dim3((N4_X + N4_W1 + N4_W2) / 256), 256, 0, stream>>>(
        x, qkv_w, proj_w, xb, wqb, wpb);

    // 1) qkv GEMM + fused LN -> q,k bf16 [B,H,N,64]; v bf16 transposed
    gemm_mfma<<<dim3(2304 / 128, MROWS / 128), 256, 0, stream>>>(
        xb, wqb, qkv_b, qb, kb, vtb, nullptr, gamma, beta, 2304, 1);

    // 2) MFMA flash attention (key-split, S^T) -> o bf16 [B,N,768]
    attn_mfma<<<dim3(SEQ / 64, BATCH * NHEAD), 256, 0, stream>>>(qb, kb, vtb, ob);

    // 3) out = o @ proj_w^T + proj_b (fp32 out)
    gemm_mfma<<<dim3(DIM / 128, MROWS / 128), 256, 0, stream>>>(
        ob, wpb, proj_b, nullptr, nullptr, nullptr, out, nullptr, nullptr, DIM, 0);
}

// Round 7
// 266.763 us; speedup vs baseline: 1.0505x; 1.0251x over previous
//
#include <hip/hip_runtime.h>
#include <stdint.h>

#define DIM   768
#define NHEAD 12
#define HD    64
#define BATCH 8
#define SEQ   1024
#define MROWS (BATCH * SEQ)   // 8192
#define EPSLN 1e-5f
#define SM_M  10.0f           // fixed softmax shift; |s| <= 8 hard after LN + 1/8 scale

typedef __attribute__((ext_vector_type(8))) short s8v;   // 8 bf16 = MFMA A/B frag
typedef __attribute__((ext_vector_type(4))) short s4v;
typedef __attribute__((ext_vector_type(4))) float f32x4;

__device__ inline short f2bf(float f) {
    union { float f; unsigned u; } v; v.f = f;
    unsigned r = v.u + 0x7FFFu + ((v.u >> 16) & 1u);   // RNE
    return (short)(r >> 16);
}
__device__ inline float bf2f(short s) {
    union { unsigned u; float f; } v;
    v.u = ((unsigned)(unsigned short)s) << 16;
    return v.f;
}
// pack two fp32 -> two bf16 in one u32 via v_perm (round-half-up)
__device__ inline unsigned pk2bf(float lo, float hi) {
    union { float f; unsigned u; } a, b; a.f = lo; b.f = hi;
    return __builtin_amdgcn_perm(b.u + 0x8000u, a.u + 0x8000u, 0x07060302u);
}
// async global->LDS, 16 B per lane (LDS dst is wave-uniform base + lane*16)
__device__ inline void gload16(const void* g, void* l) {
    __builtin_amdgcn_global_load_lds(
        (const __attribute__((address_space(1))) void*)g,
        (__attribute__((address_space(3))) void*)l, 16, 0, 0);
}

// ---------------------------------------------------------------------------
// single fp32 -> bf16 conversion pass over x | qkv_w | proj_w (float4 units)
// ---------------------------------------------------------------------------
#define N4_X (MROWS * DIM / 4)          // 1572864
#define N4_W1 (3 * DIM * DIM / 4)       // 442368
#define N4_W2 (DIM * DIM / 4)           // 147456
__global__ __launch_bounds__(256) void cvt_all(
    const float* __restrict__ x, const float* __restrict__ w1,
    const float* __restrict__ w2, short* __restrict__ dx,
    short* __restrict__ dw1, short* __restrict__ dw2)
{
    size_t i = (size_t)blockIdx.x * 256 + threadIdx.x;
    const float* s; short* d;
    if (i < N4_X)                { s = x  + i * 4;               d = dx  + i * 4; }
    else if (i < N4_X + N4_W1)   { size_t j = i - N4_X;          s = w1 + j * 4; d = dw1 + j * 4; }
    else                         { size_t j = i - N4_X - N4_W1;  s = w2 + j * 4; d = dw2 + j * 4; }
    float4 v = *(const float4*)s;
    uint2 o; o.x = pk2bf(v.x, v.y); o.y = pk2bf(v.z, v.w);
    *(uint2*)d = o;
}

// ---------------------------------------------------------------------------
// bf16 MFMA GEMM: C = A @ W^T + bias. A[M][768], W[N][768]. BM x 128 tile,
// 256 thr = 4 waves (2x2 of (BM/2)x64), BK=32, 16x16x32 MFMA. r4 structure:
// single-buffered LDS, gload16 staging, 2 barriers/iter (measured-best at
// this shape) + XOR source-chunk swizzle (conflicts 0, verified r6).
// qkv_mode (BM=128): scatter q,k bf16 [B,H,N,64] (raw, LN runs separately);
//                    v bf16 transposed [B,H,64,N].
// plain: fp32 out [M][Ncols] + bias. BM=64 -> 2x the blocks for skinny proj.
// ---------------------------------------------------------------------------
template<int BM>
__global__ __launch_bounds__(256) void gemm_mfma(
    const short* __restrict__ A, const short* __restrict__ W,
    const float* __restrict__ bias,
    short* __restrict__ oq, short* __restrict__ ok, short* __restrict__ ov,
    float* __restrict__ oplain, int Ncols, int qkv_mode)
{
    constexpr int MT = BM / 32;            // m-tiles per wave
    __shared__ __align__(16) short As[BM * 32];
    __shared__ __align__(16) short Bs[128 * 32];

    const int tid  = threadIdx.x;
    const int m0   = blockIdx.y * BM;
    const int n0   = blockIdx.x * 128;
    const int w    = tid >> 6, lane = tid & 63;
    const int quad = lane >> 4, l16 = lane & 15;
    const int wm   = (w & 1) * (BM / 2), wn = (w >> 1) * 64;
    const int cswz = ((quad ^ ((l16 >> 1) & 3))) * 8;   // swizzled k-offset

    f32x4 acc[MT][4];
#pragma unroll
    for (int i = 0; i < MT; ++i)
#pragma unroll
        for (int j = 0; j < 4; ++j) acc[i][j] = (f32x4){0.f, 0.f, 0.f, 0.f};

    for (int k0 = 0; k0 < DIM; k0 += 32) {
#pragma unroll
        for (int i = 0; i < BM / 64; ++i) {         // stage A slab
            int f   = i * 256 + tid;
            int row = f >> 2;
            int c   = (f & 3) ^ ((row >> 1) & 3);
            gload16(&A[(size_t)(m0 + row) * DIM + k0 + c * 8], &As[f * 8]);
        }
#pragma unroll
        for (int i = 0; i < 2; ++i) {               // stage B slab
            int f   = i * 256 + tid;
            int row = f >> 2;
            int c   = (f & 3) ^ ((row >> 1) & 3);
            gload16(&W[(size_t)(n0 + row) * DIM + k0 + c * 8], &Bs[f * 8]);
        }
        __syncthreads();                 // drain gload16 + all waves arrived
        s8v af[MT], bw[4];
#pragma unroll
        for (int t = 0; t < MT; ++t)
            af[t] = *(const s8v*)&As[(wm + t * 16 + l16) * 32 + cswz];
#pragma unroll
        for (int t = 0; t < 4; ++t)
            bw[t] = *(const s8v*)&Bs[(wn + t * 16 + l16) * 32 + cswz];
        __syncthreads();                 // frags in regs; next stage may overwrite
#pragma unroll
        for (int mt = 0; mt < MT; ++mt)
#pragma unroll
            for (int nt = 0; nt < 4; ++nt)
                acc[mt][nt] = __builtin_amdgcn_mfma_f32_16x16x32_bf16(
                    af[mt], bw[nt], acc[mt][nt], 0, 0, 0);
    }

    // C layout per 16x16 tile: row m = quad*4 + i, col n = l16
    if (qkv_mode) {
        const int which = n0 / DIM;        // 0=q, 1=k, 2=v (128-tiles never cross)
#pragma unroll
        for (int mt = 0; mt < MT; ++mt)
#pragma unroll
            for (int nt = 0; nt < 4; ++nt)
#pragma unroll
                for (int i = 0; i < 4; ++i) {
                    int m  = m0 + wm + mt * 16 + quad * 4 + i;
                    int n  = n0 + wn + nt * 16 + l16;
                    float cv = acc[mt][nt][i] + bias[n];
                    int bb = m >> 10, nn = m & 1023;
                    int d  = n - which * DIM;
                    int hh = d >> 6, e = d & 63;
                    if (which == 2)
                        ov[(((size_t)(bb * NHEAD + hh)) * HD + e) * SEQ + nn] = f2bf(cv);
                    else {
                        short* dst = which ? ok : oq;
                        dst[(((size_t)(bb * NHEAD + hh)) * SEQ + nn) * HD + e] = f2bf(cv);
                    }
                }
    } else {
#pragma unroll
        for (int mt = 0; mt < MT; ++mt)
#pragma unroll
            for (int nt = 0; nt < 4; ++nt)
#pragma unroll
                for (int i = 0; i < 4; ++i) {
                    int m = m0 + wm + mt * 16 + quad * 4 + i;
                    int n = n0 + wn + nt * 16 + l16;
                    oplain[(size_t)m * Ncols + n] = acc[mt][nt][i] + bias[n];
                }
    }
}

// ---------------------------------------------------------------------------
// LayerNorm(hd=64) on bf16 in-place; q rows (first half) folded by 1/8.
// q and k contiguous in ws: rows [0, 98304) = q, [98304, 196608) = k.
// ---------------------------------------------------------------------------
__global__ __launch_bounds__(256) void ln64b(
    short* __restrict__ p, const float* __restrict__ gamma,
    const float* __restrict__ beta)
{
    const int row  = blockIdx.x * 4 + (threadIdx.x >> 6);
    const int lane = threadIdx.x & 63;
    short* r = p + (size_t)row * 64;
    float v = bf2f(r[lane]);
    float s = v;
#pragma unroll
    for (int m = 1; m < 64; m <<= 1) s += __shfl_xor(s, m);
    float mu = s * (1.f / 64.f);
    float d  = v - mu;
    float s2 = d * d;
#pragma unroll
    for (int m = 1; m < 64; m <<= 1) s2 += __shfl_xor(s2, m);
    float var  = s2 * (1.f / 64.f);
    float outv = d * rsqrtf(var + EPSLN) * gamma[lane] + beta[lane];
    if (row < BATCH * NHEAD * SEQ) outv *= 0.125f;   // q rows: fold softmax scale
    r[lane] = f2bf(outv);
}

// ---------------------------------------------------------------------------
// MFMA flash attention, key-split waves, S^T formulation (unchanged from r6).
// ---------------------------------------------------------------------------
__global__ __launch_bounds__(256) void attn_mfma(
    const short* __restrict__ q, const short* __restrict__ k,
    const short* __restrict__ vt, short* __restrict__ O)
{
    const int bh   = blockIdx.y;
    const int b    = bh / NHEAD;
    const int h    = bh % NHEAD;
    const int q0   = blockIdx.x * 64;
    const int tid  = threadIdx.x;
    const int w    = tid >> 6;
    const int lane = tid & 63;
    const int quad = lane >> 4;
    const int l16  = lane & 15;

    __shared__ __align__(16) char smem[20480];   // P (main loop) / Obuf (epilogue)
    __shared__ float denom[4][64];

    short (*Pw)[40]   = (short(*)[40])(smem + (size_t)w * (64 * 40 * 2));
    float (*Obuf)[68] = (float(*)[68])smem;      // [64 q][64 e + pad]

    const size_t base   = (size_t)bh * SEQ * HD;
    const size_t vtbase = (size_t)bh * HD * SEQ;

    // hoist Q B-frags: B[k=d][n=q]: lane -> q = qt*16+l16, d = hf*32+quad*8+jj
    s8v qB[4][2];
#pragma unroll
    for (int qt = 0; qt < 4; ++qt)
#pragma unroll
        for (int hf = 0; hf < 2; ++hf)
            qB[qt][hf] = *(const s8v*)&q[base + (size_t)(q0 + qt * 16 + l16) * HD
                                         + hf * 32 + quad * 8];

    f32x4 oacc[4][4];                 // [et][qt] : O^T partials
    float lacc[4] = {0.f, 0.f, 0.f, 0.f};
#pragma unroll
    for (int a = 0; a < 4; ++a)
#pragma unroll
        for (int c = 0; c < 4; ++c) oacc[a][c] = (f32x4){0.f, 0.f, 0.f, 0.f};

#pragma unroll 2
    for (int jb = 0; jb < 8; ++jb) {
        const int kb = jb * 128 + w * 32;    // this wave's 32-key window

        // K A-frags: A[m=key][k=d]: lane -> key = kt*16+l16, d = hf*32+quad*8+jj
        s8v kA[2][2];
#pragma unroll
        for (int kt = 0; kt < 2; ++kt)
#pragma unroll
            for (int hf = 0; hf < 2; ++hf)
                kA[kt][hf] = *(const s8v*)&k[base + (size_t)(kb + kt * 16 + l16) * HD
                                             + hf * 32 + quad * 8];
        // V^T A-frags: A[m=e][k=key]: lane -> e = et*16+l16, key = quad*8+jj
        s8v va[4];
#pragma unroll
        for (int et = 0; et < 4; ++et)
            va[et] = *(const s8v*)&vt[vtbase + (size_t)(et * 16 + l16) * SEQ
                                      + kb + quad * 8];

        // ---- S^T = K Q^T, exp, packed P[q][key] -> LDS ----
#pragma unroll
        for (int qt = 0; qt < 4; ++qt)
#pragma unroll
            for (int kt = 0; kt < 2; ++kt) {
                f32x4 c = (f32x4){0.f, 0.f, 0.f, 0.f};
                c = __builtin_amdgcn_mfma_f32_16x16x32_bf16(kA[kt][0], qB[qt][0], c, 0, 0, 0);
                c = __builtin_amdgcn_mfma_f32_16x16x32_bf16(kA[kt][1], qB[qt][1], c, 0, 0, 0);
                // C: (key = kt*16 + quad*4 + i, q = qt*16 + l16)
                float p0 = __expf(c[0] - SM_M), p1 = __expf(c[1] - SM_M);
                float p2 = __expf(c[2] - SM_M), p3 = __expf(c[3] - SM_M);
                lacc[qt] += (p0 + p1) + (p2 + p3);
                uint2 pk; pk.x = pk2bf(p0, p1); pk.y = pk2bf(p2, p3);
                *(uint2*)&Pw[qt * 16 + l16][kt * 16 + quad * 4] = pk;   // b64
            }

        // ---- P^T B-frags: B[k=key][n=q] = Pw[q][key], contiguous b128 ----
        s8v pb[4];
#pragma unroll
        for (int qt = 0; qt < 4; ++qt)
            pb[qt] = *(const s8v*)&Pw[qt * 16 + l16][quad * 8];

        // ---- O^T += V^T P^T (K = 32: one MFMA per tile) ----
#pragma unroll
        for (int et = 0; et < 4; ++et)
#pragma unroll
            for (int qt = 0; qt < 4; ++qt)
                oacc[et][qt] = __builtin_amdgcn_mfma_f32_16x16x32_bf16(
                    va[et], pb[qt], oacc[et][qt], 0, 0, 0);
    }

    // ---- denominator: lane holds col q = qt*16+l16; sum across quads ----
#pragma unroll
    for (int qt = 0; qt < 4; ++qt) {
        float s = lacc[qt];
        s += __shfl_xor(s, 16);
        s += __shfl_xor(s, 32);
        denom[w][qt * 16 + l16] = s;     // 4 quads write same value: benign
    }
    __syncthreads();                     // main loop done; P region now dead

    // ---- cross-wave O sum into Obuf (overlaid on P) ----
    for (int r = 0; r < 4; ++r) {
        if (w == r) {
#pragma unroll
            for (int et = 0; et < 4; ++et)
#pragma unroll
                for (int qt = 0; qt < 4; ++qt)
#pragma unroll
                    for (int i = 0; i < 4; ++i) {
                        int e  = et * 16 + quad * 4 + i;
                        int qq = qt * 16 + l16;
                        if (r == 0) Obuf[qq][e]  = oacc[et][qt][i];
                        else        Obuf[qq][e] += oacc[et][qt][i];
                    }
        }
        __syncthreads();
    }

    // ---- scale + store: thread t -> (q = t/4, e-span = (t%4)*16) ----
    const int qq = tid >> 2;
    const int e0 = (tid & 3) * 16;
    float linv = 1.0f / (denom[0][qq] + denom[1][qq] + denom[2][qq] + denom[3][qq]);
    short* op = &O[((size_t)b * SEQ + q0 + qq) * DIM + h * HD + e0];
    uint4 o1, o2;
    o1.x = pk2bf(Obuf[qq][e0 +  0] * linv, Obuf[qq][e0 +  1] * linv);
    o1.y = pk2bf(Obuf[qq][e0 +  2] * linv, Obuf[qq][e0 +  3] * linv);
    o1.z = pk2bf(Obuf[qq][e0 +  4] * linv, Obuf[qq][e0 +  5] * linv);
    o1.w = pk2bf(Obuf[qq][e0 +  6] * linv, Obuf[qq][e0 +  7] * linv);
    o2.x = pk2bf(Obuf[qq][e0 +  8] * linv, Obuf[qq][e0 +  9] * linv);
    o2.y = pk2bf(Obuf[qq][e0 + 10] * linv, Obuf[qq][e0 + 11] * linv);
    o2.z = pk2bf(Obuf[qq][e0 + 12] * linv, Obuf[qq][e0 + 13] * linv);
    o2.w = pk2bf(Obuf[qq][e0 + 14] * linv, Obuf[qq][e0 + 15] * linv);
    *(uint4*)&op[0] = o1;
    *(uint4*)&op[8] = o2;
}

// ---------------------------------------------------------------------------
extern "C" void kernel_launch(void* const* d_in, const int* in_sizes, int n_in,
                              void* d_out, int out_size, void* d_ws, size_t ws_size,
                              hipStream_t stream)
{
    const float* x      = (const float*)d_in[0];
    const float* qkv_w  = (const float*)d_in[1];
    const float* qkv_b  = (const float*)d_in[2];
    const float* proj_w = (const float*)d_in[3];
    const float* proj_b = (const float*)d_in[4];
    const float* gamma  = (const float*)d_in[5];
    const float* beta   = (const float*)d_in[6];
    float* out = (float*)d_out;

    const size_t PER = (size_t)BATCH * NHEAD * SEQ * HD;  // 6291456
    short* qb  = (short*)d_ws;                 // bf16 q   [B,H,N,64]
    short* kb  = qb + PER;                     // bf16 k   [B,H,N,64]
    short* vtb = kb + PER;                     // bf16 v^T [B,H,64,N]
    short* ob  = vtb + PER;                    // bf16 o   [B,N,768]
    short* xb  = ob + PER;                     // bf16 x   [8192,768]
    short* wqb = xb + (size_t)MROWS * DIM;     // bf16 qkv_w [2304,768]
    short* wpb = wqb + (size_t)3 * DIM * DIM;  // bf16 proj_w [768,768]

    // 0) one fused fp32 -> bf16 conversion pass
    cvt_all<<<dim3((N4_X + N4_W1 + N4_W2) / 256), 256, 0, stream>>>(
        x, qkv_w, proj_w, xb, wqb, wpb);

    // 1) qkv GEMM -> q,k bf16 [B,H,N,64]; v bf16 transposed [B,H,64,N]
    gemm_mfma<128><<<dim3(2304 / 128, MROWS / 128), 256, 0, stream>>>(
        xb, wqb, qkv_b, qb, kb, vtb, nullptr, 2304, 1);

    // 2) LayerNorm(64) on q,k (q folded by 1/8)
    ln64b<<<dim3(2 * PER / 64 / 4), 256, 0, stream>>>(qb, gamma, beta);

    // 3) MFMA flash attention (key-split, S^T) -> o bf16 [B,N,768]
    attn_mfma<<<dim3(SEQ / 64, BATCH * NHEAD), 256, 0, stream>>>(qb, kb, vtb, ob);

    // 4) out = o @ proj_w^T + proj_b (fp32 out), 64-row tiles: 768 blocks
    gemm_mfma<64><<<dim3(DIM / 128, MROWS / 64), 256, 0, stream>>>(
        ob, wpb, proj_b, nullptr, nullptr, nullptr, out, DIM, 0);
}

// Round 8
// 257.928 us; speedup vs baseline: 1.0865x; 1.0343x over previous
//
#include <hip/hip_runtime.h>
#include <stdint.h>

#define DIM   768
#define NHEAD 12
#define HD    64
#define BATCH 8
#define SEQ   1024
#define MROWS (BATCH * SEQ)   // 8192
#define EPSLN 1e-5f
#define SM_M  10.0f           // fixed softmax shift; |s| <= 8 hard after LN + 1/8 scale

typedef __attribute__((ext_vector_type(8))) short s8v;   // 8 bf16 = MFMA A/B frag
typedef __attribute__((ext_vector_type(4))) short s4v;
typedef __attribute__((ext_vector_type(4))) float f32x4;

__device__ inline short f2bf(float f) {
    union { float f; unsigned u; } v; v.f = f;
    unsigned r = v.u + 0x7FFFu + ((v.u >> 16) & 1u);   // RNE
    return (short)(r >> 16);
}
__device__ inline float bf2f(short s) {
    union { unsigned u; float f; } v;
    v.u = ((unsigned)(unsigned short)s) << 16;
    return v.f;
}
// pack two fp32 -> two bf16 in one u32 via v_perm (round-half-up)
__device__ inline unsigned pk2bf(float lo, float hi) {
    union { float f; unsigned u; } a, b; a.f = lo; b.f = hi;
    return __builtin_amdgcn_perm(b.u + 0x8000u, a.u + 0x8000u, 0x07060302u);
}
// async global->LDS, 16 B per lane (LDS dst is wave-uniform base + lane*16)
__device__ inline void gload16(const void* g, void* l) {
    __builtin_amdgcn_global_load_lds(
        (const __attribute__((address_space(1))) void*)g,
        (__attribute__((address_space(3))) void*)l, 16, 0, 0);
}

// ---------------------------------------------------------------------------
// single fp32 -> bf16 conversion pass over x | qkv_w | proj_w (float4 units)
// ---------------------------------------------------------------------------
#define N4_X (MROWS * DIM / 4)          // 1572864
#define N4_W1 (3 * DIM * DIM / 4)       // 442368
#define N4_W2 (DIM * DIM / 4)           // 147456
__global__ __launch_bounds__(256) void cvt_all(
    const float* __restrict__ x, const float* __restrict__ w1,
    const float* __restrict__ w2, short* __restrict__ dx,
    short* __restrict__ dw1, short* __restrict__ dw2)
{
    size_t i = (size_t)blockIdx.x * 256 + threadIdx.x;
    const float* s; short* d;
    if (i < N4_X)                { s = x  + i * 4;               d = dx  + i * 4; }
    else if (i < N4_X + N4_W1)   { size_t j = i - N4_X;          s = w1 + j * 4; d = dw1 + j * 4; }
    else                         { size_t j = i - N4_X - N4_W1;  s = w2 + j * 4; d = dw2 + j * 4; }
    float4 v = *(const float4*)s;
    uint2 o; o.x = pk2bf(v.x, v.y); o.y = pk2bf(v.z, v.w);
    *(uint2*)d = o;
}

// ---------------------------------------------------------------------------
// bf16 MFMA GEMM: C = A @ W^T + bias. A[M][768], W[N][768]. BM x 128 tile,
// 256 thr = 4 waves (2x2 of (BM/2)x64), BK=64 (12 K-iters: half the exposed
// vmcnt-drains of BK=32), 16x16x32 MFMA in two ks-halves.
// XOR source-chunk swizzle (8 chunks/row): store c = c' ^ (row&7), read
// chunk (ks*4+quad) ^ (l16&7) -> b128 frag reads 2-way/free (0 conflicts).
// qkv_mode (BM=128): scatter q,k bf16 [B,H,N,64]; v bf16 transposed.
// plain: fp32 out [M][Ncols] + bias (BM=64 for skinny proj: 768 blocks).
// ---------------------------------------------------------------------------
template<int BM>
__global__ __launch_bounds__(256) void gemm_mfma(
    const short* __restrict__ A, const short* __restrict__ W,
    const float* __restrict__ bias,
    short* __restrict__ oq, short* __restrict__ ok, short* __restrict__ ov,
    float* __restrict__ oplain, int Ncols, int qkv_mode)
{
    constexpr int MT = BM / 32;            // m-tiles per wave
    __shared__ __align__(16) short As[BM * 64];
    __shared__ __align__(16) short Bs[128 * 64];

    const int tid  = threadIdx.x;
    const int m0   = blockIdx.y * BM;
    const int n0   = blockIdx.x * 128;
    const int w    = tid >> 6, lane = tid & 63;
    const int quad = lane >> 4, l16 = lane & 15;
    const int wm   = (w & 1) * (BM / 2), wn = (w >> 1) * 64;
    const int rsw  = l16 & 7;              // read-row swizzle key (row&7 == l16&7)

    f32x4 acc[MT][4];
#pragma unroll
    for (int i = 0; i < MT; ++i)
#pragma unroll
        for (int j = 0; j < 4; ++j) acc[i][j] = (f32x4){0.f, 0.f, 0.f, 0.f};

    for (int k0 = 0; k0 < DIM; k0 += 64) {
#pragma unroll
        for (int i = 0; i < BM / 32; ++i) {         // stage A slab (BM x 64)
            int f   = i * 256 + tid;
            int row = f >> 3;
            int c   = (f & 7) ^ (row & 7);
            gload16(&A[(size_t)(m0 + row) * DIM + k0 + c * 8], &As[f * 8]);
        }
#pragma unroll
        for (int i = 0; i < 4; ++i) {               // stage B slab (128 x 64)
            int f   = i * 256 + tid;
            int row = f >> 3;
            int c   = (f & 7) ^ (row & 7);
            gload16(&W[(size_t)(n0 + row) * DIM + k0 + c * 8], &Bs[f * 8]);
        }
        __syncthreads();                 // drain gload16 + all waves arrived
#pragma unroll
        for (int ks = 0; ks < 2; ++ks) {
            const int ch = ((ks * 4 + quad) ^ rsw) * 8;
            s8v af[MT], bw[4];
#pragma unroll
            for (int t = 0; t < MT; ++t)
                af[t] = *(const s8v*)&As[(wm + t * 16 + l16) * 64 + ch];
#pragma unroll
            for (int t = 0; t < 4; ++t)
                bw[t] = *(const s8v*)&Bs[(wn + t * 16 + l16) * 64 + ch];
#pragma unroll
            for (int mt = 0; mt < MT; ++mt)
#pragma unroll
                for (int nt = 0; nt < 4; ++nt)
                    acc[mt][nt] = __builtin_amdgcn_mfma_f32_16x16x32_bf16(
                        af[mt], bw[nt], acc[mt][nt], 0, 0, 0);
        }
        __syncthreads();                 // frags consumed; next stage may overwrite
    }

    // C layout per 16x16 tile: row m = quad*4 + i, col n = l16
    if (qkv_mode) {
        const int which = n0 / DIM;        // 0=q, 1=k, 2=v (128-tiles never cross)
#pragma unroll
        for (int mt = 0; mt < MT; ++mt)
#pragma unroll
            for (int nt = 0; nt < 4; ++nt)
#pragma unroll
                for (int i = 0; i < 4; ++i) {
                    int m  = m0 + wm + mt * 16 + quad * 4 + i;
                    int n  = n0 + wn + nt * 16 + l16;
                    float cv = acc[mt][nt][i] + bias[n];
                    int bb = m >> 10, nn = m & 1023;
                    int d  = n - which * DIM;
                    int hh = d >> 6, e = d & 63;
                    if (which == 2)
                        ov[(((size_t)(bb * NHEAD + hh)) * HD + e) * SEQ + nn] = f2bf(cv);
                    else {
                        short* dst = which ? ok : oq;
                        dst[(((size_t)(bb * NHEAD + hh)) * SEQ + nn) * HD + e] = f2bf(cv);
                    }
                }
    } else {
#pragma unroll
        for (int mt = 0; mt < MT; ++mt)
#pragma unroll
            for (int nt = 0; nt < 4; ++nt)
#pragma unroll
                for (int i = 0; i < 4; ++i) {
                    int m = m0 + wm + mt * 16 + quad * 4 + i;
                    int n = n0 + wn + nt * 16 + l16;
                    oplain[(size_t)m * Ncols + n] = acc[mt][nt][i] + bias[n];
                }
    }
}

// ---------------------------------------------------------------------------
// LayerNorm(hd=64) on bf16 in-place; q rows (first half) folded by 1/8.
// ---------------------------------------------------------------------------
__global__ __launch_bounds__(256) void ln64b(
    short* __restrict__ p, const float* __restrict__ gamma,
    const float* __restrict__ beta)
{
    const int row  = blockIdx.x * 4 + (threadIdx.x >> 6);
    const int lane = threadIdx.x & 63;
    short* r = p + (size_t)row * 64;
    float v = bf2f(r[lane]);
    float s = v;
#pragma unroll
    for (int m = 1; m < 64; m <<= 1) s += __shfl_xor(s, m);
    float mu = s * (1.f / 64.f);
    float d  = v - mu;
    float s2 = d * d;
#pragma unroll
    for (int m = 1; m < 64; m <<= 1) s2 += __shfl_xor(s2, m);
    float var  = s2 * (1.f / 64.f);
    float outv = d * rsqrtf(var + EPSLN) * gamma[lane] + beta[lane];
    if (row < BATCH * NHEAD * SEQ) outv *= 0.125f;   // q rows: fold softmax scale
    r[lane] = f2bf(outv);
}

// ---------------------------------------------------------------------------
// MFMA flash attention, key-split waves, S^T formulation (r6 structure;
// epilogue Obuf traffic now float4-vectorized).
// ---------------------------------------------------------------------------
__global__ __launch_bounds__(256) void attn_mfma(
    const short* __restrict__ q, const short* __restrict__ k,
    const short* __restrict__ vt, short* __restrict__ O)
{
    const int bh   = blockIdx.y;
    const int b    = bh / NHEAD;
    const int h    = bh % NHEAD;
    const int q0   = blockIdx.x * 64;
    const int tid  = threadIdx.x;
    const int w    = tid >> 6;
    const int lane = tid & 63;
    const int quad = lane >> 4;
    const int l16  = lane & 15;

    __shared__ __align__(16) char smem[20480];   // P (main loop) / Obuf (epilogue)
    __shared__ float denom[4][64];

    short (*Pw)[40]   = (short(*)[40])(smem + (size_t)w * (64 * 40 * 2));
    float (*Obuf)[68] = (float(*)[68])smem;      // [64 q][64 e + pad]

    const size_t base   = (size_t)bh * SEQ * HD;
    const size_t vtbase = (size_t)bh * HD * SEQ;

    // hoist Q B-frags: B[k=d][n=q]: lane -> q = qt*16+l16, d = hf*32+quad*8+jj
    s8v qB[4][2];
#pragma unroll
    for (int qt = 0; qt < 4; ++qt)
#pragma unroll
        for (int hf = 0; hf < 2; ++hf)
            qB[qt][hf] = *(const s8v*)&q[base + (size_t)(q0 + qt * 16 + l16) * HD
                                         + hf * 32 + quad * 8];

    f32x4 oacc[4][4];                 // [et][qt] : O^T partials
    float lacc[4] = {0.f, 0.f, 0.f, 0.f};
#pragma unroll
    for (int a = 0; a < 4; ++a)
#pragma unroll
        for (int c = 0; c < 4; ++c) oacc[a][c] = (f32x4){0.f, 0.f, 0.f, 0.f};

#pragma unroll 2
    for (int jb = 0; jb < 8; ++jb) {
        const int kb = jb * 128 + w * 32;    // this wave's 32-key window

        // K A-frags: A[m=key][k=d]: lane -> key = kt*16+l16, d = hf*32+quad*8+jj
        s8v kA[2][2];
#pragma unroll
        for (int kt = 0; kt < 2; ++kt)
#pragma unroll
            for (int hf = 0; hf < 2; ++hf)
                kA[kt][hf] = *(const s8v*)&k[base + (size_t)(kb + kt * 16 + l16) * HD
                                             + hf * 32 + quad * 8];
        // V^T A-frags: A[m=e][k=key]: lane -> e = et*16+l16, key = quad*8+jj
        s8v va[4];
#pragma unroll
        for (int et = 0; et < 4; ++et)
            va[et] = *(const s8v*)&vt[vtbase + (size_t)(et * 16 + l16) * SEQ
                                      + kb + quad * 8];

        // ---- S^T = K Q^T, exp, packed P[q][key] -> LDS ----
#pragma unroll
        for (int qt = 0; qt < 4; ++qt)
#pragma unroll
            for (int kt = 0; kt < 2; ++kt) {
                f32x4 c = (f32x4){0.f, 0.f, 0.f, 0.f};
                c = __builtin_amdgcn_mfma_f32_16x16x32_bf16(kA[kt][0], qB[qt][0], c, 0, 0, 0);
                c = __builtin_amdgcn_mfma_f32_16x16x32_bf16(kA[kt][1], qB[qt][1], c, 0, 0, 0);
                // C: (key = kt*16 + quad*4 + i, q = qt*16 + l16)
                float p0 = __expf(c[0] - SM_M), p1 = __expf(c[1] - SM_M);
                float p2 = __expf(c[2] - SM_M), p3 = __expf(c[3] - SM_M);
                lacc[qt] += (p0 + p1) + (p2 + p3);
                uint2 pk; pk.x = pk2bf(p0, p1); pk.y = pk2bf(p2, p3);
                *(uint2*)&Pw[qt * 16 + l16][kt * 16 + quad * 4] = pk;   // b64
            }

        // ---- P^T B-frags: B[k=key][n=q] = Pw[q][key], contiguous b128 ----
        s8v pb[4];
#pragma unroll
        for (int qt = 0; qt < 4; ++qt)
            pb[qt] = *(const s8v*)&Pw[qt * 16 + l16][quad * 8];

        // ---- O^T += V^T P^T (K = 32: one MFMA per tile) ----
#pragma unroll
        for (int et = 0; et < 4; ++et)
#pragma unroll
            for (int qt = 0; qt < 4; ++qt)
                oacc[et][qt] = __builtin_amdgcn_mfma_f32_16x16x32_bf16(
                    va[et], pb[qt], oacc[et][qt], 0, 0, 0);
    }

    // ---- denominator: lane holds col q = qt*16+l16; sum across quads ----
#pragma unroll
    for (int qt = 0; qt < 4; ++qt) {
        float s = lacc[qt];
        s += __shfl_xor(s, 16);
        s += __shfl_xor(s, 32);
        denom[w][qt * 16 + l16] = s;     // 4 quads write same value: benign
    }
    __syncthreads();                     // main loop done; P region now dead

    // ---- cross-wave O sum into Obuf (float4: e = et*16+quad*4 .. +3) ----
    for (int r = 0; r < 4; ++r) {
        if (w == r) {
#pragma unroll
            for (int et = 0; et < 4; ++et)
#pragma unroll
                for (int qt = 0; qt < 4; ++qt) {
                    float* dst = &Obuf[qt * 16 + l16][et * 16 + quad * 4];
                    float4 ov;
                    if (r == 0) ov = make_float4(0.f, 0.f, 0.f, 0.f);
                    else        ov = *(float4*)dst;
                    ov.x += oacc[et][qt][0]; ov.y += oacc[et][qt][1];
                    ov.z += oacc[et][qt][2]; ov.w += oacc[et][qt][3];
                    *(float4*)dst = ov;
                }
        }
        __syncthreads();
    }

    // ---- scale + store: thread t -> (q = t/4, e-span = (t%4)*16) ----
    const int qq = tid >> 2;
    const int e0 = (tid & 3) * 16;
    float linv = 1.0f / (denom[0][qq] + denom[1][qq] + denom[2][qq] + denom[3][qq]);
    float4 f0 = *(float4*)&Obuf[qq][e0];
    float4 f1 = *(float4*)&Obuf[qq][e0 + 4];
    float4 f2 = *(float4*)&Obuf[qq][e0 + 8];
    float4 f3 = *(float4*)&Obuf[qq][e0 + 12];
    short* op = &O[((size_t)b * SEQ + q0 + qq) * DIM + h * HD + e0];
    uint4 o1, o2;
    o1.x = pk2bf(f0.x * linv, f0.y * linv);
    o1.y = pk2bf(f0.z * linv, f0.w * linv);
    o1.z = pk2bf(f1.x * linv, f1.y * linv);
    o1.w = pk2bf(f1.z * linv, f1.w * linv);
    o2.x = pk2bf(f2.x * linv, f2.y * linv);
    o2.y = pk2bf(f2.z * linv, f2.w * linv);
    o2.z = pk2bf(f3.x * linv, f3.y * linv);
    o2.w = pk2bf(f3.z * linv, f3.w * linv);
    *(uint4*)&op[0] = o1;
    *(uint4*)&op[8] = o2;
}

// ---------------------------------------------------------------------------
extern "C" void kernel_launch(void* const* d_in, const int* in_sizes, int n_in,
                              void* d_out, int out_size, void* d_ws, size_t ws_size,
                              hipStream_t stream)
{
    const float* x      = (const float*)d_in[0];
    const float* qkv_w  = (const float*)d_in[1];
    const float* qkv_b  = (const float*)d_in[2];
    const float* proj_w = (const float*)d_in[3];
    const float* proj_b = (const float*)d_in[4];
    const float* gamma  = (const float*)d_in[5];
    const float* beta   = (const float*)d_in[6];
    float* out = (float*)d_out;

    const size_t PER = (size_t)BATCH * NHEAD * SEQ * HD;  // 6291456
    short* qb  = (short*)d_ws;                 // bf16 q   [B,H,N,64]
    short* kb  = qb + PER;                     // bf16 k   [B,H,N,64]
    short* vtb = kb + PER;                     // bf16 v^T [B,H,64,N]
    short* ob  = vtb + PER;                    // bf16 o   [B,N,768]
    short* xb  = ob + PER;                     // bf16 x   [8192,768]
    short* wqb = xb + (size_t)MROWS * DIM;     // bf16 qkv_w [2304,768]
    short* wpb = wqb + (size_t)3 * DIM * DIM;  // bf16 proj_w [768,768]

    // 0) one fused fp32 -> bf16 conversion pass
    cvt_all<<<dim3((N4_X + N4_W1 + N4_W2) / 256), 256, 0, stream>>>(
        x, qkv_w, proj_w, xb, wqb, wpb);

    // 1) qkv GEMM -> q,k bf16 [B,H,N,64]; v bf16 transposed [B,H,64,N]
    gemm_mfma<128><<<dim3(2304 / 128, MROWS / 128), 256, 0, stream>>>(
        xb, wqb, qkv_b, qb, kb, vtb, nullptr, 2304, 1);

    // 2) LayerNorm(64) on q,k (q folded by 1/8)
    ln64b<<<dim3(2 * PER / 64 / 4), 256, 0, stream>>>(qb, gamma, beta);

    // 3) MFMA flash attention (key-split, S^T) -> o bf16 [B,N,768]
    attn_mfma<<<dim3(SEQ / 64, BATCH * NHEAD), 256, 0, stream>>>(qb, kb, vtb, ob);

    // 4) out = o @ proj_w^T + proj_b (fp32 out), 64-row tiles: 768 blocks
    gemm_mfma<64><<<dim3(DIM / 128, MROWS / 64), 256, 0, stream>>>(
        ob, wpb, proj_b, nullptr, nullptr, nullptr, out, DIM, 0);
}